// Round 5
// baseline (118.254 us; speedup 1.0000x reference)
//
#include <hip/hip_runtime.h>
#include <stdint.h>

// ---- problem dims ----
#define NROWS 8192
#define LDIM  1024
#define HDIM  512

typedef __attribute__((ext_vector_type(8))) short short8;
typedef __attribute__((ext_vector_type(4))) float f32x4;
typedef __attribute__((ext_vector_type(4))) unsigned int u32x4;

typedef __attribute__((address_space(3))) unsigned int lds_uint;
typedef const __attribute__((address_space(1))) unsigned int glob_uint;

// ---- zero partition: 16B chunks over d_out floats [4, 67108864) ----
#define Z_MEGA_START 0L
#define Z_MEGA_CNT   6815744L   // 104 MB
#define ZB_MEGA      3328
#define Z_G1_START   6815744L
#define Z_G1_CNT     5242880L   // 80 MB
#define ZB_G1        2560
#define Z_G2_START   12058624L
#define Z_G2_CNT     4194304L   // 64 MB
#define ZB_G2        2048
#define Z_RW_START   16252928L
#define Z_RW_CNT     524287L    // ~8 MB (last block clamps)
#define ZB_RW        256

__device__ __forceinline__ void llds16(const void* g, void* l) {
  __builtin_amdgcn_global_load_lds((glob_uint*)g, (lds_uint*)l, 16, 0, 0);
}

__device__ __forceinline__ unsigned short f2bf(float f) {
  union { float f; unsigned int u; } c; c.f = f;
  unsigned int u = c.u;
  unsigned int r = (u + 0x7fffu + ((u >> 16) & 1u)) >> 16;
  return (unsigned short)r;
}

__device__ __forceinline__ float bfbits2f(unsigned int hi16) {
  union { unsigned int u; float f; } c; c.u = hi16;
  return c.f;
}

__device__ __forceinline__ void zero_chunks(u32x4* __restrict__ out16, long c0, long c1, int tid) {
  u32x4 z = {0u, 0u, 0u, 0u};
  for (long i = c0 + tid; i < c1; i += 256) out16[i] = z;
}

// ---- mega BW kernel ----
// blocks [0,3328): zero 104MB | [3328,7424): x->bf16 | [7424,8192): coalesced weight transpose
__global__ __launch_bounds__(256) void mega_bw_kernel(const float* __restrict__ x,
                                                      const float* __restrict__ Wfc,
                                                      const float* __restrict__ Wa,
                                                      const float* __restrict__ Wb,
                                                      unsigned short* __restrict__ xb,
                                                      unsigned short* __restrict__ WfcT,
                                                      unsigned short* __restrict__ WabT,
                                                      float* __restrict__ out) {
  __shared__ float tile[32][33];
  const int bid = blockIdx.x;
  const int tid = threadIdx.x;
  if (bid < ZB_MEGA) {
    long c0 = Z_MEGA_START + (long)bid * 2048;
    long lim = Z_MEGA_START + Z_MEGA_CNT;
    long c1 = c0 + 2048 < lim ? c0 + 2048 : lim;
    zero_chunks((u32x4*)(out + 4), c0, c1, tid);
    if (bid == 0 && tid == 0) {
      out[2] = 0.f; out[3] = 0.f;                 // head floats (before 16B-aligned region)
      out[67108864] = 0.f; out[67108865] = 0.f;   // tail floats
    }
    return;
  }
  if (bid < ZB_MEGA + 4096) {
    // conv: x f32 -> bf16, 8 elems/thread
    long i = ((long)(bid - ZB_MEGA) * 256 + tid) * 8;
    float4 v0 = *(const float4*)(x + i);
    float4 v1 = *(const float4*)(x + i + 4);
    union { unsigned short s[8]; uint4 u; } o;
    o.s[0] = f2bf(v0.x); o.s[1] = f2bf(v0.y); o.s[2] = f2bf(v0.z); o.s[3] = f2bf(v0.w);
    o.s[4] = f2bf(v1.x); o.s[5] = f2bf(v1.y); o.s[6] = f2bf(v1.z); o.s[7] = f2bf(v1.w);
    *(uint4*)(xb + i) = o.u;
    return;
  }
  // coalesced 32x32 tile transpose + f32->bf16
  // WabT layout: row c (c in [0,512)): g=c>>5, r=c&31; r<16 -> Wa col g*16+r ; r>=16 -> Wb col g*16+(r-16)
  int tt = bid - (ZB_MEGA + 4096);  // 0..767
  const float* src; unsigned short* dst; int srcn, dstk, k0, n0; int mode;
  if (tt < 512) {          // Wfc [1024][512] -> WfcT [512][1024]
    src = Wfc; dst = WfcT; srcn = 512; dstk = 1024; mode = 0;
    k0 = (tt >> 4) * 32; n0 = (tt & 15) * 32;
  } else if (tt < 640) {   // Wa [512][256] -> WabT (a-halves)
    int t2 = tt - 512;
    src = Wa; dst = WabT; srcn = 256; dstk = 512; mode = 1;
    k0 = (t2 >> 3) * 32; n0 = (t2 & 7) * 32;
  } else {                 // Wb [512][256] -> WabT (b-halves)
    int t2 = tt - 640;
    src = Wb; dst = WabT; srcn = 256; dstk = 512; mode = 2;
    k0 = (t2 >> 3) * 32; n0 = (t2 & 7) * 32;
  }
  int r = tid >> 3, c4 = (tid & 7) * 4;
  float4 v = *(const float4*)(src + (long)(k0 + r) * srcn + n0 + c4);
  tile[r][c4 + 0] = v.x; tile[r][c4 + 1] = v.y; tile[r][c4 + 2] = v.z; tile[r][c4 + 3] = v.w;
  __syncthreads();
  union { unsigned short s[4]; uint2 u; } o;
#pragma unroll
  for (int j = 0; j < 4; ++j) o.s[j] = f2bf(tile[c4 + j][r]);
  int n = n0 + r;  // source col
  long crow;
  if (mode == 0) crow = n;
  else crow = (long)(((n >> 4) << 5) + (n & 15) + (mode == 2 ? 16 : 0));
  *(uint2*)(dst + crow * dstk + k0 + c4) = o.u;
}

// ---- bf16 GEMM, 128x128 tile, BK=32, 4 waves (2x2), 4x4 frags/wave ----
// A[M][K] x Bt[N][K] -> relu(acc+bias) -> bf16 out[M][N]; tail blocks zero duty.
__global__ __launch_bounds__(256) void gemm1_kernel(const unsigned short* __restrict__ A,
                                                    const unsigned short* __restrict__ Bt,
                                                    const float* __restrict__ bias,
                                                    unsigned short* __restrict__ out,
                                                    int M, int N, int K,
                                                    float* __restrict__ zout) {
  constexpr int BM = 128, BN = 128, BK = 32;
  __shared__ unsigned short sA[2][BM * BK];
  __shared__ unsigned short sB[2][BN * BK];
  const int tid = threadIdx.x;
  const int nbn = N / BN;
  const int ncomp = (M / BM) * nbn;
  if ((int)blockIdx.x >= ncomp) {
    int zb = (int)blockIdx.x - ncomp;
    long c0 = Z_G1_START + (long)zb * 2048;
    long lim = Z_G1_START + Z_G1_CNT;
    long c1 = c0 + 2048 < lim ? c0 + 2048 : lim;
    zero_chunks((u32x4*)(zout + 4), c0, c1, tid);
    return;
  }
  const int lane = tid & 63;
  const int wv = tid >> 6;
  const int wm = wv >> 1;
  const int wn = wv & 1;
  const int bm = blockIdx.x / nbn, bn = blockIdx.x % nbn;
  const int row0 = bm * BM, col0 = bn * BN;

  f32x4 acc[4][4] = {};
  const int nk = K / BK;

  auto stage = [&](int buf, int kt) {
#pragma unroll
    for (int r = 0; r < 2; ++r) {
      int c = r * 256 + tid;
      int arow = c >> 2, acb = (c & 3) * 8;
      const unsigned short* g = A + (long)(row0 + arow) * K + kt * BK + acb;
      unsigned short* l = (unsigned short*)&sA[buf][(r * 256 + wv * 64) * 8];
      llds16(g, l);
    }
#pragma unroll
    for (int r = 0; r < 2; ++r) {
      int c = r * 256 + tid;
      int brow = c >> 2, bcb = (c & 3) * 8;
      const unsigned short* g = Bt + (long)(col0 + brow) * K + kt * BK + bcb;
      unsigned short* l = (unsigned short*)&sB[buf][(r * 256 + wv * 64) * 8];
      llds16(g, l);
    }
  };

  stage(0, 0);
  __syncthreads();

  for (int kt = 0; kt < nk; ++kt) {
    int cur = kt & 1;
    if (kt + 1 < nk) stage(cur ^ 1, kt + 1);
    const unsigned short* bA = sA[cur];
    const unsigned short* bB = sB[cur];
    short8 af[4], bfr[4];
#pragma unroll
    for (int fm = 0; fm < 4; ++fm)
      af[fm] = *(const short8*)&bA[(wm * 64 + fm * 16 + (lane & 15)) * BK + (lane >> 4) * 8];
#pragma unroll
    for (int fn = 0; fn < 4; ++fn)
      bfr[fn] = *(const short8*)&bB[(wn * 64 + fn * 16 + (lane & 15)) * BK + (lane >> 4) * 8];
#pragma unroll
    for (int fm = 0; fm < 4; ++fm)
#pragma unroll
      for (int fn = 0; fn < 4; ++fn)
        acc[fm][fn] = __builtin_amdgcn_mfma_f32_16x16x32_bf16(af[fm], bfr[fn], acc[fm][fn], 0, 0, 0);
    __syncthreads();
  }

#pragma unroll
  for (int fm = 0; fm < 4; ++fm) {
#pragma unroll
    for (int fn = 0; fn < 4; ++fn) {
#pragma unroll
      for (int i = 0; i < 4; ++i) {
        int row = row0 + wm * 64 + fm * 16 + (lane >> 4) * 4 + i;
        int col = col0 + wn * 64 + fn * 16 + (lane & 15);
        float v = acc[fm][fn][i] + bias[col];
        v = v > 0.f ? v : 0.f;
        out[(long)row * N + col] = f2bf(v);
      }
    }
  }
}

// ---- gemm2 fused: t = h @ WabT^T (permuted layout), gated score partials in epilogue ----
// spart[(bn*2+wn)][row] = sum over this wave's 64 cols of tanh(a+ba)*sigmoid(b+bb)*Wc
__global__ __launch_bounds__(256) void gemm2_fused(const unsigned short* __restrict__ A,
                                                   const unsigned short* __restrict__ Bt,
                                                   const float* __restrict__ ba_,
                                                   const float* __restrict__ bb_,
                                                   const float* __restrict__ Wc,
                                                   float* __restrict__ spart,
                                                   float* __restrict__ zout) {
  constexpr int BM = 128, BN = 128, BK = 32;
  constexpr int M = NROWS, N = HDIM, K = HDIM;
  __shared__ unsigned short sA[2][BM * BK];
  __shared__ unsigned short sB[2][BN * BK];
  const int tid = threadIdx.x;
  const int nbn = N / BN;
  const int ncomp = (M / BM) * nbn;
  if ((int)blockIdx.x >= ncomp) {
    int zb = (int)blockIdx.x - ncomp;
    long c0 = Z_G2_START + (long)zb * 2048;
    long lim = Z_G2_START + Z_G2_CNT;
    long c1 = c0 + 2048 < lim ? c0 + 2048 : lim;
    zero_chunks((u32x4*)(zout + 4), c0, c1, tid);
    return;
  }
  const int lane = tid & 63;
  const int wv = tid >> 6;
  const int wm = wv >> 1;
  const int wn = wv & 1;
  const int bm = blockIdx.x / nbn, bn = blockIdx.x % nbn;
  const int row0 = bm * BM, col0 = bn * BN;

  f32x4 acc[4][4] = {};
  const int nk = K / BK;

  auto stage = [&](int buf, int kt) {
#pragma unroll
    for (int r = 0; r < 2; ++r) {
      int c = r * 256 + tid;
      int arow = c >> 2, acb = (c & 3) * 8;
      const unsigned short* g = A + (long)(row0 + arow) * K + kt * BK + acb;
      unsigned short* l = (unsigned short*)&sA[buf][(r * 256 + wv * 64) * 8];
      llds16(g, l);
    }
#pragma unroll
    for (int r = 0; r < 2; ++r) {
      int c = r * 256 + tid;
      int brow = c >> 2, bcb = (c & 3) * 8;
      const unsigned short* g = Bt + (long)(col0 + brow) * K + kt * BK + bcb;
      unsigned short* l = (unsigned short*)&sB[buf][(r * 256 + wv * 64) * 8];
      llds16(g, l);
    }
  };

  stage(0, 0);
  __syncthreads();

  for (int kt = 0; kt < nk; ++kt) {
    int cur = kt & 1;
    if (kt + 1 < nk) stage(cur ^ 1, kt + 1);
    const unsigned short* bA = sA[cur];
    const unsigned short* bB = sB[cur];
    short8 af[4], bfr[4];
#pragma unroll
    for (int fm = 0; fm < 4; ++fm)
      af[fm] = *(const short8*)&bA[(wm * 64 + fm * 16 + (lane & 15)) * BK + (lane >> 4) * 8];
#pragma unroll
    for (int fn = 0; fn < 4; ++fn)
      bfr[fn] = *(const short8*)&bB[(wn * 64 + fn * 16 + (lane & 15)) * BK + (lane >> 4) * 8];
#pragma unroll
    for (int fm = 0; fm < 4; ++fm)
#pragma unroll
      for (int fn = 0; fn < 4; ++fn)
        acc[fm][fn] = __builtin_amdgcn_mfma_f32_16x16x32_bf16(af[fm], bfr[fn], acc[fm][fn], 0, 0, 0);
    __syncthreads();
  }

  // fused gated-score epilogue
  const int colbase = col0 + wn * 64;                   // multiple of 32
  const int d0 = (colbase >> 5) * 16 + (lane & 15);     // d for p=0 ; p=1 -> d0+16
  float wc0 = Wc[d0],  wc1 = Wc[d0 + 16];
  float av0 = ba_[d0], av1 = ba_[d0 + 16];
  float bv0 = bb_[d0], bv1 = bb_[d0 + 16];
  float* sp = spart + (long)(bn * 2 + wn) * NROWS;
#pragma unroll
  for (int fm = 0; fm < 4; ++fm) {
#pragma unroll
    for (int i = 0; i < 4; ++i) {
      float a0 = acc[fm][0][i] + av0, b0 = acc[fm][1][i] + bv0;
      float a1 = acc[fm][2][i] + av1, b1 = acc[fm][3][i] + bv1;
      float v = tanhf(a0) * (1.f / (1.f + __expf(-b0))) * wc0
              + tanhf(a1) * (1.f / (1.f + __expf(-b1))) * wc1;
#pragma unroll
      for (int off = 1; off < 16; off <<= 1) v += __shfl_xor(v, off);
      if ((lane & 15) == 0) {
        int row = row0 + wm * 64 + fm * 16 + (lane >> 4) * 4 + i;
        sp[row] = v;
      }
    }
  }
}

// ---- redwsum: 64 work blocks (score reduce + softmax weights + weighted colsum) + 256 zero-tail ----
__global__ __launch_bounds__(256) void redwsum_kernel(const float* __restrict__ spart,
                                                      const float* __restrict__ bc,
                                                      const unsigned short* __restrict__ h,
                                                      float* __restrict__ part,
                                                      float* __restrict__ out) {
  const int b = blockIdx.x;
  const int t = threadIdx.x;
  if (b >= 64) {
    int zb = b - 64;
    long c0 = Z_RW_START + (long)zb * 2048;
    long lim = Z_RW_START + Z_RW_CNT;
    long c1 = c0 + 2048 < lim ? c0 + 2048 : lim;
    zero_chunks((u32x4*)(out + 4), c0, c1, t);
    return;
  }
  __shared__ float sc[NROWS];
  __shared__ float red[256];
  __shared__ float warr[128];
  const float bcv = bc[0];
  float lmax = -1e30f;
  for (int k = t; k < NROWS; k += 256) {
    float s = bcv;
#pragma unroll
    for (int q = 0; q < 8; ++q) s += spart[q * NROWS + k];
    sc[k] = s;
    lmax = fmaxf(lmax, s);
  }
  red[t] = lmax; __syncthreads();
  for (int s = 128; s; s >>= 1) { if (t < s) red[t] = fmaxf(red[t], red[t + s]); __syncthreads(); }
  float m = fmaxf(red[0], 0.f);
  __syncthreads();
  float lsum = 0.f;
  for (int k = t; k < NROWS; k += 256) lsum += __expf(sc[k] - m);
  red[t] = lsum; __syncthreads();
  for (int s = 128; s; s >>= 1) { if (t < s) red[t] += red[t + s]; __syncthreads(); }
  float e0 = __expf(-m);
  float Z = red[0] + 67100672.0f * e0;  // (n*n - n) * e0
  float c0w = 8191.0f * e0 / Z;         // (n-1)*e0/Z
  if (t < 128) warr[t] = __expf(sc[b * 128 + t] - m) / Z + c0w;
  __syncthreads();
  float a0 = 0.f, a1 = 0.f;
  for (int i = 0; i < 128; ++i) {
    float wi = warr[i];
    unsigned int hv = *(const unsigned int*)&h[(long)(b * 128 + i) * 512 + t * 2];
    a0 += wi * bfbits2f(hv << 16);
    a1 += wi * bfbits2f(hv & 0xffff0000u);
  }
  part[b * 512 + t * 2] = a0;
  part[b * 512 + t * 2 + 1] = a1;
}

// ---- final: block 0 = M+logits ; blocks 1..32 = A_raw diagonal (runs after all zeroing) ----
__global__ __launch_bounds__(512) void final_kernel(const float* __restrict__ part,
                                                    const float* __restrict__ spart,
                                                    const float* __restrict__ bc,
                                                    const float* __restrict__ Wcls,
                                                    const float* __restrict__ bcls,
                                                    float* __restrict__ out) {
  const int t = threadIdx.x;
  if (blockIdx.x > 0) {
    if (t < 256) {
      int row = (blockIdx.x - 1) * 256 + t;
      float s = bc[0];
#pragma unroll
      for (int q = 0; q < 8; ++q) s += spart[q * NROWS + row];
      out[2 + 8193L * row] = s;
    }
    return;
  }
  __shared__ float Msh[512];
  float s = 0.f;
  for (int b = 0; b < 64; ++b) s += part[b * 512 + t];
  Msh[t] = s;
  __syncthreads();
  if (t < 64) {
    float p0 = 0.f, p1 = 0.f;
    for (int j = t; j < 512; j += 64) { p0 += Msh[j] * Wcls[j * 2]; p1 += Msh[j] * Wcls[j * 2 + 1]; }
#pragma unroll
    for (int off = 32; off; off >>= 1) { p0 += __shfl_down(p0, off); p1 += __shfl_down(p1, off); }
    if (t == 0) { out[0] = p0 + bcls[0]; out[1] = p1 + bcls[1]; }
  }
}

extern "C" void kernel_launch(void* const* d_in, const int* in_sizes, int n_in,
                              void* d_out, int out_size, void* d_ws, size_t ws_size,
                              hipStream_t stream) {
  const float* x    = (const float*)d_in[0];
  const float* Wfc  = (const float*)d_in[1];
  const float* bfc  = (const float*)d_in[2];
  const float* Wa   = (const float*)d_in[3];
  const float* ba   = (const float*)d_in[4];
  const float* Wb   = (const float*)d_in[5];
  const float* bb   = (const float*)d_in[6];
  const float* Wc   = (const float*)d_in[7];
  const float* bc   = (const float*)d_in[8];
  const float* Wcls = (const float*)d_in[9];
  const float* bcls = (const float*)d_in[10];
  float* out = (float*)d_out;
  char* ws = (char*)d_ws;

  // workspace layout (bytes)
  unsigned short* xb    = (unsigned short*)(ws + 0);         // 16,777,216
  unsigned short* WfcT  = (unsigned short*)(ws + 16777216);  //  1,048,576
  unsigned short* WabT  = (unsigned short*)(ws + 17825792);  //    524,288
  unsigned short* hbuf  = (unsigned short*)(ws + 18350080);  //  8,388,608
  float*          spart = (float*)(ws + 26738688);           //    262,144 (8 x 8192 f32)
  float*          part  = (float*)(ws + 27000832);           //    131,072 (64 x 512 f32)

  // 1) mega BW kernel: 104MB zeros + x->bf16 + coalesced weight transpose (permuted WabT)
  mega_bw_kernel<<<ZB_MEGA + 4096 + 768, 256, 0, stream>>>(x, Wfc, Wa, Wb, xb, WfcT, WabT, out);
  // 2) h = relu(x @ Wfc + bfc); tail blocks zero 80MB
  gemm1_kernel<<<(NROWS / 128) * (HDIM / 128) + ZB_G1, 256, 0, stream>>>(
      xb, WfcT, bfc, hbuf, NROWS, HDIM, LDIM, out);
  // 3) fused gemm2 + gated score partials; tail blocks zero 64MB
  gemm2_fused<<<(NROWS / 128) * (HDIM / 128) + ZB_G2, 256, 0, stream>>>(
      hbuf, WabT, ba, bb, Wc, spart, out);
  // 4) score reduce + softmax weights + weighted colsum (+ 8MB zero tail)
  redwsum_kernel<<<64 + ZB_RW, 256, 0, stream>>>(spart, bc, hbuf, part, out);
  // 5) M + logits ; A_raw diagonal
  final_kernel<<<33, 512, 0, stream>>>(part, spart, bc, Wcls, bcls, out);
}